// Round 5
// baseline (435.449 us; speedup 1.0000x reference)
//
#include <hip/hip_runtime.h>
#include <hip/hip_bf16.h>
#include <stdint.h>

typedef unsigned short u16;
typedef unsigned int   u32;

#define N_NODES 50000
#define N_EDGES 400000
#define DDIM    512

typedef __attribute__((ext_vector_type(8))) __bf16 bf16x8;
typedef __attribute__((ext_vector_type(4))) float  f32x4;

// ---------- helpers ----------
__device__ __forceinline__ float bflo(u32 d) { return __builtin_bit_cast(float, d << 16); }
__device__ __forceinline__ float bfhi(u32 d) { return __builtin_bit_cast(float, d & 0xffff0000u); }
__device__ __forceinline__ u16 f2bf(float f) {
    u32 u = __builtin_bit_cast(u32, f);
    u32 r = u + 0x7fffu + ((u >> 16) & 1u);   // RNE; inputs finite
    return (u16)(r >> 16);
}
__device__ __forceinline__ u32 pack2(float a, float b) {
    return (u32)f2bf(a) | ((u32)f2bf(b) << 16);
}
__device__ __forceinline__ void gload_lds16(const void* g, void* l) {
    __builtin_amdgcn_global_load_lds(
        (const __attribute__((address_space(1))) void*)g,
        (__attribute__((address_space(3))) void*)l, 16, 0, 0);
}

// ---------- 0. x (f32) -> xb (bf16) ----------
__global__ void cvt_k(const float* __restrict__ x, u16* __restrict__ xb) {
    int i = blockIdx.x * 256 + threadIdx.x;          // 8 elements per thread
    const float4* p = (const float4*)(x + (size_t)i * 8);
    float4 a = p[0], b = p[1];
    uint4 o;
    o.x = pack2(a.x, a.y); o.y = pack2(a.z, a.w);
    o.z = pack2(b.x, b.y); o.w = pack2(b.z, b.w);
    ((uint4*)xb)[i] = o;
}

// ---------- 1. histogram of dst ----------
__global__ void hist_k(const int* __restrict__ dst, int* __restrict__ counts) {
    int e = blockIdx.x * 256 + threadIdx.x;
    if (e < N_EDGES) atomicAdd(&counts[dst[e]], 1);
}

// ---------- 2. three-phase exclusive scan (49 chunks of 1024) ----------
#define NCHUNK 49
__global__ __launch_bounds__(1024) void scanA_k(const int* __restrict__ counts, int* __restrict__ csum) {
    __shared__ int ws[16];
    int t = threadIdx.x, b = blockIdx.x;
    int i = b * 1024 + t;
    int v = (i < N_NODES) ? counts[i] : 0;
    for (int d = 32; d; d >>= 1) v += __shfl_down(v, d);
    if ((t & 63) == 0) ws[t >> 6] = v;
    __syncthreads();
    if (t < 16) {
        int s = ws[t];
        for (int d = 8; d; d >>= 1) s += __shfl_down(s, d);
        if (t == 0) csum[b] = s;
    }
}
__global__ void scanB_k(int* __restrict__ csum) {   // 64 threads, exclusive in-place
    int t = threadIdx.x;
    int v = (t < NCHUNK) ? csum[t] : 0;
    int s = v;
    for (int d = 1; d < 64; d <<= 1) { int u = __shfl_up(s, d); if (t >= d) s += u; }
    if (t < NCHUNK) csum[t] = s - v;
}
__global__ __launch_bounds__(1024) void scanC_k(const int* __restrict__ counts, const int* __restrict__ csum,
                                                int* __restrict__ offsets, int* __restrict__ cursor) {
    __shared__ int wsum[16];
    int t = threadIdx.x, b = blockIdx.x;
    int i = b * 1024 + t;
    int lane = t & 63, w = t >> 6;
    int v = (i < N_NODES) ? counts[i] : 0;
    int s = v;
    for (int d = 1; d < 64; d <<= 1) { int u = __shfl_up(s, d); if (lane >= d) s += u; }
    if (lane == 63) wsum[w] = s;
    __syncthreads();
    if (t < 16) {
        int ww = wsum[t], ss = ww;
        for (int d = 1; d < 16; d <<= 1) { int u = __shfl_up(ss, d); if (t >= d) ss += u; }
        wsum[t] = ss - ww;
    }
    __syncthreads();
    int excl = (s - v) + wsum[w] + csum[b];
    if (i < N_NODES) { offsets[i] = excl; cursor[i] = excl; }
}

// ---------- 3. fill CSR ----------
__global__ void fill_k(const int* __restrict__ src, const int* __restrict__ dst,
                       int* __restrict__ cursor, int* __restrict__ esrc) {
    int e = blockIdx.x * 256 + threadIdx.x;
    if (e < N_EDGES) {
        int d = dst[e];
        int p = atomicAdd(&cursor[d], 1);
        esrc[p] = src[e];
    }
}

// ---------- 4. prep weights ----------
__global__ void prepw_k(const float* __restrict__ W1, const float* __restrict__ W2,
                        const float* __restrict__ b1, const float* __restrict__ b2,
                        u16* __restrict__ Wt12, u16* __restrict__ Wt2, float* __restrict__ b12) {
    int idx = blockIdx.x * 256 + threadIdx.x;          // = k*512 + n
    int k = idx >> 9, n = idx & 511;
    float w1 = W1[idx], w2 = W2[idx];
    Wt12[n * 512 + k] = f2bf(w1 + w2);
    Wt2[n * 512 + k]  = f2bf(w2);
    if (idx < 512) b12[idx] = b1[idx] + b2[idx];
}

// ---------- 5. aggregate from bf16 xb: meanNeg = bf16(-mean) ----------
__device__ __forceinline__ void addrow(float* acc, uint4 v) {
    acc[0] += bflo(v.x); acc[1] += bfhi(v.x);
    acc[2] += bflo(v.y); acc[3] += bfhi(v.y);
    acc[4] += bflo(v.z); acc[5] += bfhi(v.z);
    acc[6] += bflo(v.w); acc[7] += bfhi(v.w);
}
__global__ __launch_bounds__(256) void agg_k(const u16* __restrict__ xb,
                                             const int* __restrict__ offsets,
                                             const int* __restrict__ counts,
                                             const int* __restrict__ esrc,
                                             u16* __restrict__ meanNeg) {
    int nid = blockIdx.x * 4 + (threadIdx.x >> 6);
    if (nid >= N_NODES) return;
    int lane = threadIdx.x & 63;
    int off = offsets[nid], deg = counts[nid];
    float acc[8] = {0, 0, 0, 0, 0, 0, 0, 0};
    const size_t lo = (size_t)lane * 8;
    int e = 0;
    for (; e + 7 < deg; e += 8) {
        int s0 = esrc[off + e],     s1 = esrc[off + e + 1];
        int s2 = esrc[off + e + 2], s3 = esrc[off + e + 3];
        int s4 = esrc[off + e + 4], s5 = esrc[off + e + 5];
        int s6 = esrc[off + e + 6], s7 = esrc[off + e + 7];
        uint4 v0 = *(const uint4*)(xb + (size_t)s0 * DDIM + lo);
        uint4 v1 = *(const uint4*)(xb + (size_t)s1 * DDIM + lo);
        uint4 v2 = *(const uint4*)(xb + (size_t)s2 * DDIM + lo);
        uint4 v3 = *(const uint4*)(xb + (size_t)s3 * DDIM + lo);
        uint4 v4 = *(const uint4*)(xb + (size_t)s4 * DDIM + lo);
        uint4 v5 = *(const uint4*)(xb + (size_t)s5 * DDIM + lo);
        uint4 v6 = *(const uint4*)(xb + (size_t)s6 * DDIM + lo);
        uint4 v7 = *(const uint4*)(xb + (size_t)s7 * DDIM + lo);
        addrow(acc, v0); addrow(acc, v1); addrow(acc, v2); addrow(acc, v3);
        addrow(acc, v4); addrow(acc, v5); addrow(acc, v6); addrow(acc, v7);
    }
    for (; e + 3 < deg; e += 4) {
        int s0 = esrc[off + e],     s1 = esrc[off + e + 1];
        int s2 = esrc[off + e + 2], s3 = esrc[off + e + 3];
        uint4 v0 = *(const uint4*)(xb + (size_t)s0 * DDIM + lo);
        uint4 v1 = *(const uint4*)(xb + (size_t)s1 * DDIM + lo);
        uint4 v2 = *(const uint4*)(xb + (size_t)s2 * DDIM + lo);
        uint4 v3 = *(const uint4*)(xb + (size_t)s3 * DDIM + lo);
        addrow(acc, v0); addrow(acc, v1); addrow(acc, v2); addrow(acc, v3);
    }
    for (; e < deg; e++) {
        int s0 = esrc[off + e];
        addrow(acc, *(const uint4*)(xb + (size_t)s0 * DDIM + lo));
    }
    float scale = (deg > 0) ? (-1.0f / (float)deg) : 0.0f;
    uint4 o;
    o.x = pack2(acc[0] * scale, acc[1] * scale);
    o.y = pack2(acc[2] * scale, acc[3] * scale);
    o.z = pack2(acc[4] * scale, acc[5] * scale);
    o.w = pack2(acc[6] * scale, acc[7] * scale);
    *(uint4*)(meanNeg + (size_t)nid * DDIM + lo) = o;
}

// ---------- 6. GEMM: out = xb@Wt12^T + meanNeg@Wt2^T + b12 (f32 out, masked) ----------
// BK=64 (16 barrier-iters), 1D grid with n-fastest swizzle for L3 A-reuse.
__global__ __launch_bounds__(256) void gemm_k(const u16* __restrict__ xb,
                                              const float* __restrict__ x,
                                              const u16* __restrict__ meanNeg,
                                              const u16* __restrict__ Wt12,
                                              const u16* __restrict__ Wt2,
                                              const float* __restrict__ b12,
                                              const int* __restrict__ counts,
                                              float* __restrict__ out) {
    __shared__ u16 As[128 * 64];   // 16 KB
    __shared__ u16 Bs[128 * 64];   // 16 KB
    const int bid = blockIdx.x;
    const int m0 = (bid >> 2) * 128;
    const int n0 = (bid & 3) * 128;
    const int tid = threadIdx.x;
    const int lane = tid & 63;
    const int wid  = tid >> 6;
    const int wm = wid >> 1, wn = wid & 1;
    const int quad = lane >> 4, lr = lane & 15;

    f32x4 acc[4][4] = {};

    // staging: per wave 4 gloads/operand, 8 rows x 64k each; lane -> row lane>>3, k (lane&7)*8
    const int kk = (lane & 7) * 8;
    int arow[4], brow[4];
    #pragma unroll
    for (int t = 0; t < 4; t++) {
        int r = wid * 32 + t * 8 + (lane >> 3);
        int ar = m0 + r; if (ar >= N_NODES) ar = N_NODES - 1;
        arow[t] = ar;
        brow[t] = n0 + r;
    }

    for (int pass = 0; pass < 2; pass++) {
        const u16* __restrict__ A = pass ? meanNeg : xb;
        const u16* __restrict__ B = pass ? Wt2 : Wt12;
        for (int k0 = 0; k0 < 512; k0 += 64) {
            #pragma unroll
            for (int t = 0; t < 4; t++) {
                int rblk = wid * 32 + t * 8;
                gload_lds16(A + (size_t)arow[t] * DDIM + k0 + kk, &As[rblk * 64]);
                gload_lds16(B + (size_t)brow[t] * DDIM + k0 + kk, &Bs[rblk * 64]);
            }
            __syncthreads();
            #pragma unroll
            for (int ks = 0; ks < 2; ks++) {
                bf16x8 af[4], bfr[4];
                #pragma unroll
                for (int i = 0; i < 4; i++)
                    af[i] = *(const bf16x8*)&As[(wm * 64 + i * 16 + lr) * 64 + ks * 32 + quad * 8];
                #pragma unroll
                for (int j = 0; j < 4; j++)
                    bfr[j] = *(const bf16x8*)&Bs[(wn * 64 + j * 16 + lr) * 64 + ks * 32 + quad * 8];
                #pragma unroll
                for (int i = 0; i < 4; i++)
                    #pragma unroll
                    for (int j = 0; j < 4; j++)
                        acc[i][j] = __builtin_amdgcn_mfma_f32_16x16x32_bf16(af[i], bfr[j], acc[i][j], 0, 0, 0);
            }
            __syncthreads();
        }
    }

    // epilogue: C/D layout col=lane&15, row=quad*4+r ; f32 output
    #pragma unroll
    for (int i = 0; i < 4; i++) {
        #pragma unroll
        for (int r = 0; r < 4; r++) {
            int grow = m0 + wm * 64 + i * 16 + quad * 4 + r;
            if (grow >= N_NODES) continue;
            int cnt = counts[grow];
            #pragma unroll
            for (int j = 0; j < 4; j++) {
                int gcol = n0 + wn * 64 + j * 16 + lr;
                float v;
                if (cnt > 0) v = acc[i][j][r] + b12[gcol];
                else         v = x[(size_t)grow * DDIM + gcol];   // exact passthrough
                out[(size_t)grow * DDIM + gcol] = v;
            }
        }
    }
}

// ---------- launch ----------
extern "C" void kernel_launch(void* const* d_in, const int* in_sizes, int n_in,
                              void* d_out, int out_size, void* d_ws, size_t ws_size,
                              hipStream_t stream) {
    const float* x  = (const float*)d_in[0];
    const int* src  = (const int*)d_in[1];
    const int* dst  = (const int*)d_in[2];
    const float* W1 = (const float*)d_in[3];
    const float* b1 = (const float*)d_in[4];
    const float* W2 = (const float*)d_in[5];
    const float* b2 = (const float*)d_in[6];
    float* out = (float*)d_out;

    char* ws = (char*)d_ws;
    size_t o = 0;
    auto alloc = [&](size_t bytes) { char* p = ws + o; o += (bytes + 255) & ~(size_t)255; return p; };
    int* counts   = (int*)alloc((size_t)N_NODES * 4);
    int* offsets  = (int*)alloc((size_t)N_NODES * 4);
    int* cursor   = (int*)alloc((size_t)N_NODES * 4);
    int* csum     = (int*)alloc((size_t)NCHUNK * 4);
    int* esrc     = (int*)alloc((size_t)N_EDGES * 4);
    u16* Wt12     = (u16*)alloc((size_t)512 * 512 * 2);
    u16* Wt2      = (u16*)alloc((size_t)512 * 512 * 2);
    float* b12    = (float*)alloc((size_t)512 * 4);
    u16* xb       = (u16*)alloc((size_t)N_NODES * DDIM * 2);
    u16* meanNeg  = (u16*)alloc((size_t)N_NODES * DDIM * 2);   // ~106 MB total ws
    (void)ws_size; (void)n_in; (void)in_sizes; (void)out_size;

    hipMemsetAsync(counts, 0, (size_t)N_NODES * 4, stream);
    cvt_k<<<(N_NODES * DDIM / 8) / 256, 256, 0, stream>>>(x, xb);
    hist_k<<<(N_EDGES + 255) / 256, 256, 0, stream>>>(dst, counts);
    scanA_k<<<NCHUNK, 1024, 0, stream>>>(counts, csum);
    scanB_k<<<1, 64, 0, stream>>>(csum);
    scanC_k<<<NCHUNK, 1024, 0, stream>>>(counts, csum, offsets, cursor);
    fill_k<<<(N_EDGES + 255) / 256, 256, 0, stream>>>(src, dst, cursor, esrc);
    prepw_k<<<(512 * 512) / 256, 256, 0, stream>>>(W1, W2, b1, b2, Wt12, Wt2, b12);
    agg_k<<<(N_NODES + 3) / 4, 256, 0, stream>>>(xb, offsets, counts, esrc, meanNeg);
    gemm_k<<<391 * 4, 256, 0, stream>>>(
        xb, x, meanNeg, Wt12, Wt2, b12, counts, out);
}